// Round 5
// baseline (189.297 us; speedup 1.0000x reference)
//
#include <hip/hip_runtime.h>

// Fused deformable-conv net — r16: LDS gathers restored (r15b proved
// global/L3 gathers stall 47% of issue: cross-XCD latency unhidden;
// r10 proved LDS gathers hide at 95% busy), with lane efficiency fixed
// by an interleaved image-mod-4 mapping:
//   block = 256 threads <-> 4 whole images; img = tid&3, lc = tid>>2;
//   thread's cells = {lc, lc+64, lc+128, lc+192 if <196} via a
//   #pragma unroll 1 loop (one body copy). Waves 1-3 issue 3 body
//   passes, wave 0 issues 4 (last 16/64 lanes): 13 passes / 12.25
//   useful = 94.2% lane eff (r10: 76.6%) with r10-identical staging
//   cost per cell (3600 words / 784 cells = 4.6).
// Images never straddle blocks: no atomics, no memset, no segmented
// reduce. Reduce = 4 fixed __shfl_xor (masks 4,8,16,32 sum residue
// classes mod 4; lanes 0-3 hold imgs 0-3) -> red[4][4][10] -> 40
// threads write out directly (+b_fc). Single kernel, no workspace.
// r10 champion body FROZEN VERBATIM (the only proven 64-VGPR codegen;
// r14's rewrite hit 128 VGPR).

#define NPOS  784
#define NPOOL 1568
#define CELLS 196
#define TPB   256
#define WP    30
#define PIMG  900

__global__ __launch_bounds__(256) void deform_net_kernel(
    const float* __restrict__ x,       // (B,1,28,28)
    const float* __restrict__ w_off,   // (18,1,3,3)
    const float* __restrict__ b_off,   // (18,)
    const float* __restrict__ w_conv,  // (8,1,3,3)
    const float* __restrict__ w_fc,    // (10,1568)
    const float* __restrict__ b_fc,    // (10,)
    float* __restrict__ out,           // (B,10)
    int Btot)
{
    __shared__ float xs[4 * PIMG];     // 4 zero-padded 30x30 images
    __shared__ float wo_s[162];
    __shared__ float bo_s[18];
    __shared__ float wc_s[72];
    __shared__ float red[4][4][10];    // [wave][img-slot][channel]

    const int tid      = threadIdx.x;
    const int imgFirst = blockIdx.x * 4;

    if (tid < 162) wo_s[tid] = w_off[tid];
    if (tid < 18)  bo_s[tid] = b_off[tid];
    if (tid < 72)  wc_s[tid] = w_conv[tid];

    // Stage 4 zero-padded images. Layout xs[s*900 + r*30 + c] == xs[i].
    for (int i = tid; i < 4 * PIMG; i += TPB) {
        int s = i / PIMG;              // image slot 0..3
        int v = i - s * PIMG;          // 0..899
        int r = v / WP, c = v - r * WP;
        int img = imgFirst + s;
        float val = 0.f;
        if (img < Btot && r >= 1 && r <= 28 && c >= 1 && c <= 28)
            val = x[(size_t)img * NPOS + (r - 1) * 28 + (c - 1)];
        xs[i] = val;
    }
    __syncthreads();

    const int imgSlot = tid & 3;       // which of the block's 4 images
    const int lc      = tid >> 2;      // 0..63: cell residue class
    const float* __restrict__ xsl = xs + imgSlot * PIMG;

    float fc[10];
    #pragma unroll
    for (int c = 0; c < 10; c++) fc[c] = 0.f;

    #pragma unroll 1
    for (int it = 0; it < 4; ++it) {
        const int cell = lc + (it << 6);   // lc, lc+64, lc+128, lc+192
        if (cell < CELLS) {
            const int ph = cell / 14, pw = cell - (cell / 14) * 14;
            const int h0 = 2 * ph, w0 = 2 * pw;

            // 4x4 padded-image neighborhood covering all 4 positions' taps.
            float nb[16];
            #pragma unroll
            for (int i = 0; i < 4; i++)
                #pragma unroll
                for (int j = 0; j < 4; j++)
                    nb[i * 4 + j] = xsl[(h0 + i) * WP + (w0 + j)];

            // ---- r10 champion body, FROZEN (k-outer, acc[4][8]) ----
            float acc[4][8];
            #pragma unroll
            for (int p = 0; p < 4; p++)
                #pragma unroll
                for (int o = 0; o < 8; o++) acc[p][o] = 0.f;

            #pragma unroll
            for (int k = 0; k < 9; k++) {          // deform tap
                const int kx = k / 3, ky = k % 3;
                #pragma unroll
                for (int p = 0; p < 4; p++) {      // position within pool cell
                    const int dh = p >> 1, dw = p & 1;

                    // offset channels k (x), k+9 (y): 3x3 conv at (h0+dh, w0+dw)
                    float offx = bo_s[k], offy = bo_s[k + 9];
                    #pragma unroll
                    for (int t = 0; t < 9; t++) {
                        float nv = nb[(dh + t / 3) * 4 + (dw + t % 3)];
                        offx = fmaf(wo_s[k * 9 + t],       nv, offx);
                        offy = fmaf(wo_s[(k + 9) * 9 + t], nv, offy);
                    }

                    // sample coords in padded frame: p0=(h+1,w+1), pn=(kx-1,ky-1)
                    float p_x = (float)(h0 + dh + kx) + offx;
                    float p_y = (float)(w0 + dw + ky) + offy;

                    float q0x = floorf(p_x), q0y = floorf(p_y);
                    float qltx = __builtin_amdgcn_fmed3f(q0x,       0.f, 29.f);
                    float qlty = __builtin_amdgcn_fmed3f(q0y,       0.f, 29.f);
                    float qrbx = __builtin_amdgcn_fmed3f(q0x + 1.f, 0.f, 29.f);
                    float qrby = __builtin_amdgcn_fmed3f(q0y + 1.f, 0.f, 29.f);
                    float px   = __builtin_amdgcn_fmed3f(p_x,       0.f, 29.f);
                    float py   = __builtin_amdgcn_fmed3f(p_y,       0.f, 29.f);

                    float gltx = 1.f + (qltx - px);
                    float glty = 1.f + (qlty - py);
                    float grbx = 1.f - (qrbx - px);
                    float grby = 1.f - (qrby - py);

                    int ilx = (int)qltx, ily = (int)qlty;
                    int irx = (int)qrbx, iry = (int)qrby;

                    float xlt = xsl[ilx * WP + ily];
                    float xrb = xsl[irx * WP + iry];
                    float xlb = xsl[ilx * WP + iry];
                    float xrt = xsl[irx * WP + ily];

                    // factored bilinear combine (same clip semantics)
                    float s = gltx * (glty * xlt + grby * xlb)
                            + grbx * (glty * xrt + grby * xrb);

                    #pragma unroll
                    for (int o = 0; o < 8; o++)
                        acc[p][o] = fmaf(wc_s[o * 9 + k], s, acc[p][o]);
                }
            }

            // relu + 2x2 maxpool in registers, then FC partials (o-outer).
            #pragma unroll
            for (int o = 0; o < 8; o++) {
                float m = fmaxf(fmaxf(acc[0][o], acc[1][o]),
                                fmaxf(acc[2][o], acc[3][o]));
                m = fmaxf(m, 0.f);
                const float* wrow = w_fc + o * CELLS + cell; // o*196+cell
                #pragma unroll
                for (int c = 0; c < 10; c++)
                    fc[c] = fmaf(m, wrow[c * NPOOL], fc[c]);
            }
            // ---- end frozen body ----
        }
    }

    // Residue-class (mod 4) butterfly: masks 4,8,16,32 sum lanes with the
    // same (lane&3) == same image. Lanes 0-3 end with imgs 0-3 partials.
    #pragma unroll
    for (int c = 0; c < 10; c++) {
        fc[c] += __shfl_xor(fc[c], 4, 64);
        fc[c] += __shfl_xor(fc[c], 8, 64);
        fc[c] += __shfl_xor(fc[c], 16, 64);
        fc[c] += __shfl_xor(fc[c], 32, 64);
    }
    const int wave = tid >> 6, lane = tid & 63;
    if (lane < 4) {
        #pragma unroll
        for (int c = 0; c < 10; c++) red[wave][lane][c] = fc[c];
    }
    __syncthreads();

    // Cross-wave sum, direct store (each image fully owned by this block).
    if (tid < 40) {
        const int s = tid / 10, c = tid - (tid / 10) * 10;
        const int img = imgFirst + s;
        if (img < Btot)
            out[img * 10 + c] = red[0][s][c] + red[1][s][c]
                              + red[2][s][c] + red[3][s][c] + b_fc[c];
    }
}

extern "C" void kernel_launch(void* const* d_in, const int* in_sizes, int n_in,
                              void* d_out, int out_size, void* d_ws, size_t ws_size,
                              hipStream_t stream) {
    const float* x      = (const float*)d_in[0];
    const float* w_off  = (const float*)d_in[1];
    const float* b_off  = (const float*)d_in[2];
    const float* w_conv = (const float*)d_in[3];
    const float* w_fc   = (const float*)d_in[4];
    const float* b_fc   = (const float*)d_in[5];
    float* out = (float*)d_out;

    const int B = in_sizes[0] / NPOS;
    const int nblk = (B + 3) / 4;      // 1024 for B=4096
    deform_net_kernel<<<nblk, TPB, 0, stream>>>(x, w_off, b_off, w_conv,
                                                w_fc, b_fc, out, B);
}

// Round 6
// 180.569 us; speedup vs baseline: 1.0483x; 1.0483x over previous
//
#include <hip/hip_runtime.h>

// Fused deformable-conv net — r17: per-POSITION threads, one image per
// 832-thread block (13 waves). Lane eff 784/832 = 94.2% vs r10's 76.6%,
// achieved while satisfying every constraint proven by r13-r16:
//   - LDS gathers (r15: global/L3 gathers stall 47% of issue),
//   - body straight-line, executed ONCE per thread (r14/r16: any outer
//     loop or restructure around the body blows VGPR 64->128/208),
//   - one image per block (r13: straddle machinery costs VGPR+staging).
// The body is the frozen r10 body's single-position slice: nb[9],
// acc[8], 9-tap k-loop, identical med3/floor/factored-bilinear math.
// Per-thread state shrinks structurally: nb 16->9, acc 32->8, fc 10->3.
// Glue: 2x2 maxpool = 2 shfl_xor (masks 1,2) in the 4-lane position
// group; FC split 4-way across the group (channels c = (tid&3)+4j);
// residue-4 butterfly (masks 4,8,16,32) -> red[13][4][3] -> 10 threads
// store out + b_fc. No atomics, no workspace, single kernel.

#define NPOS  784
#define NPOOL 1568
#define CELLS 196
#define TPB   832
#define WP    30
#define PIMG  900

__global__ __launch_bounds__(832) void deform_net_kernel(
    const float* __restrict__ x,       // (B,1,28,28)
    const float* __restrict__ w_off,   // (18,1,3,3)
    const float* __restrict__ b_off,   // (18,)
    const float* __restrict__ w_conv,  // (8,1,3,3)
    const float* __restrict__ w_fc,    // (10,1568)
    const float* __restrict__ b_fc,    // (10,)
    float* __restrict__ out)           // (B,10)
{
    __shared__ float xs[PIMG];         // one zero-padded 30x30 image
    __shared__ float wo_s[162];
    __shared__ float bo_s[18];
    __shared__ float wc_s[72];
    __shared__ float red[13][4][3];    // [wave][lane-residue][channel-slot]

    const int tid = threadIdx.x;
    const int b   = blockIdx.x;

    if (tid < 162) wo_s[tid] = w_off[tid];
    if (tid < 18)  bo_s[tid] = b_off[tid];
    if (tid < 72)  wc_s[tid] = w_conv[tid];

    // Stage zero-padded image into LDS.
    const float* __restrict__ xb = x + (size_t)b * NPOS;
    for (int i = tid; i < PIMG; i += TPB) {
        int r = i / WP, c = i - r * WP;
        float v = 0.f;
        if (r >= 1 && r <= 28 && c >= 1 && c <= 28)
            v = xb[(r - 1) * 28 + (c - 1)];
        xs[i] = v;
    }
    __syncthreads();

    const int cell = tid >> 2;         // pool cell 0..195
    const int p    = tid & 3;          // position within 2x2 pool window

    float m[8];
    #pragma unroll
    for (int o = 0; o < 8; o++) m[o] = 0.f;
    float fc0 = 0.f, fc1 = 0.f, fc2 = 0.f;

    if (tid < NPOS) {
        const int ph = cell / 14, pw = cell - (cell / 14) * 14;
        const int h = 2 * ph + (p >> 1);    // conv output row 0..27
        const int w = 2 * pw + (p & 1);     // conv output col 0..27

        // 3x3 padded-image neighborhood for this position's offset conv.
        float nb[9];
        #pragma unroll
        for (int i = 0; i < 3; i++)
            #pragma unroll
            for (int j = 0; j < 3; j++)
                nb[i * 3 + j] = xs[(h + i) * WP + (w + j)];

        float acc[8];
        #pragma unroll
        for (int o = 0; o < 8; o++) acc[o] = 0.f;

        // ---- frozen r10 body, single-position slice (k-outer) ----
        #pragma unroll
        for (int k = 0; k < 9; k++) {          // deform tap
            const int kx = k / 3, ky = k % 3;

            // offset channels k (x) and k+9 (y): 3x3 conv at (h, w)
            float offx = bo_s[k], offy = bo_s[k + 9];
            #pragma unroll
            for (int t = 0; t < 9; t++) {
                float nv = nb[t];
                offx = fmaf(wo_s[k * 9 + t],       nv, offx);
                offy = fmaf(wo_s[(k + 9) * 9 + t], nv, offy);
            }

            // sample coords in padded frame: p0=(h+1,w+1), pn=(kx-1,ky-1)
            float p_x = (float)(h + kx) + offx;
            float p_y = (float)(w + ky) + offy;

            float q0x = floorf(p_x), q0y = floorf(p_y);
            float qltx = __builtin_amdgcn_fmed3f(q0x,       0.f, 29.f);
            float qlty = __builtin_amdgcn_fmed3f(q0y,       0.f, 29.f);
            float qrbx = __builtin_amdgcn_fmed3f(q0x + 1.f, 0.f, 29.f);
            float qrby = __builtin_amdgcn_fmed3f(q0y + 1.f, 0.f, 29.f);
            float px   = __builtin_amdgcn_fmed3f(p_x,       0.f, 29.f);
            float py   = __builtin_amdgcn_fmed3f(p_y,       0.f, 29.f);

            float gltx = 1.f + (qltx - px);
            float glty = 1.f + (qlty - py);
            float grbx = 1.f - (qrbx - px);
            float grby = 1.f - (qrby - py);

            int ilx = (int)qltx, ily = (int)qlty;
            int irx = (int)qrbx, iry = (int)qrby;

            float xlt = xs[ilx * WP + ily];
            float xrb = xs[irx * WP + iry];
            float xlb = xs[ilx * WP + iry];
            float xrt = xs[irx * WP + ily];

            // factored bilinear combine (same clip semantics)
            float s = gltx * (glty * xlt + grby * xlb)
                    + grbx * (glty * xrt + grby * xrb);

            #pragma unroll
            for (int o = 0; o < 8; o++)
                acc[o] = fmaf(wc_s[o * 9 + k], s, acc[o]);
        }
        // ---- end frozen body slice ----

        #pragma unroll
        for (int o = 0; o < 8; o++) m[o] = acc[o];
    }

    // 2x2 maxpool across the 4-lane position group, then relu.
    // (Invalid threads hold 0 and sit in their own groups.)
    #pragma unroll
    for (int o = 0; o < 8; o++) {
        m[o] = fmaxf(m[o], __shfl_xor(m[o], 1, 64));
        m[o] = fmaxf(m[o], __shfl_xor(m[o], 2, 64));
        m[o] = fmaxf(m[o], 0.f);
    }

    // FC partials: group lane l3 takes channels c = l3, l3+4, l3+8(<10).
    if (tid < NPOS) {
        const int l3 = tid & 3;
        {
            const float* wcol = w_fc + l3 * NPOOL + cell;       // c = l3
            float s0 = 0.f;
            #pragma unroll
            for (int o = 0; o < 8; o++) s0 = fmaf(m[o], wcol[o * CELLS], s0);
            fc0 = s0;
        }
        {
            const float* wcol = w_fc + (l3 + 4) * NPOOL + cell; // c = l3+4
            float s0 = 0.f;
            #pragma unroll
            for (int o = 0; o < 8; o++) s0 = fmaf(m[o], wcol[o * CELLS], s0);
            fc1 = s0;
        }
        if (l3 < 2) {
            const float* wcol = w_fc + (l3 + 8) * NPOOL + cell; // c = l3+8
            float s0 = 0.f;
            #pragma unroll
            for (int o = 0; o < 8; o++) s0 = fmaf(m[o], wcol[o * CELLS], s0);
            fc2 = s0;
        }
    }

    // Residue-4 butterfly: masks 4..32 sum lanes with equal (lane&3),
    // i.e. same channel set, across the wave's 16 cells.
    #pragma unroll
    for (int sh = 4; sh <= 32; sh <<= 1) {
        fc0 += __shfl_xor(fc0, sh, 64);
        fc1 += __shfl_xor(fc1, sh, 64);
        fc2 += __shfl_xor(fc2, sh, 64);
    }
    const int wave = tid >> 6, lane = tid & 63;
    if (lane < 4) {
        red[wave][lane][0] = fc0;
        red[wave][lane][1] = fc1;
        red[wave][lane][2] = fc2;   // garbage for lane>=2; never read
    }
    __syncthreads();

    // Final: channel c lives at residue c&3, slot c>>2; sum 13 waves.
    if (tid < 10) {
        const int r4 = tid & 3, j = tid >> 2;
        float v = b_fc[tid];
        #pragma unroll
        for (int wv = 0; wv < 13; wv++) v += red[wv][r4][j];
        out[b * 10 + tid] = v;
    }
}

extern "C" void kernel_launch(void* const* d_in, const int* in_sizes, int n_in,
                              void* d_out, int out_size, void* d_ws, size_t ws_size,
                              hipStream_t stream) {
    const float* x      = (const float*)d_in[0];
    const float* w_off  = (const float*)d_in[1];
    const float* b_off  = (const float*)d_in[2];
    const float* w_conv = (const float*)d_in[3];
    const float* w_fc   = (const float*)d_in[4];
    const float* b_fc   = (const float*)d_in[5];
    float* out = (float*)d_out;

    const int B = in_sizes[0] / NPOS;
    deform_net_kernel<<<B, TPB, 0, stream>>>(x, w_off, b_off, w_conv,
                                             w_fc, b_fc, out);
}

// Round 8
// 140.705 us; speedup vs baseline: 1.3453x; 1.2833x over previous
//
#include <hip/hip_runtime.h>

// Fused deformable-conv net — r18b: byte-identical resubmit of r18
// (container infra failed twice; no counter evidence against the
// design — same situation as r15->r15b, where resubmission ran clean).
//
// r18 design: r10 champion structure with TWO images per 448-thread
// (7-wave) block. Lane eff 392/448 = 87.5% vs r10's 196/256 = 76.6%,
// while preserving every property the r13-r17 ledger proved necessary:
//   - LDS gathers            (r15: L3 gathers stall 47% of issue)
//   - body straight-line, executed ONCE per thread (r14/r16: loops or
//     restructure -> VGPR 128/208)
//   - 4-way position ILP in one thread (r17: single-position slice ->
//     52% busy, latency-exposed)
//   - 64-VGPR frozen body verbatim; only xsl base + cim indexing vary
// Images are block-owned: no atomics, no memset, no tail (4096/2=2048
// blocks). Exactly one wave (wave 3, tids 192-255) straddles the image
// boundary at tid 196 -> dual two-temp butterfly (r15b-proven codegen);
// other waves single butterfly. red[7][2][10] zero-init, final 20
// threads sum 7 waves + b_fc and store directly.

#define NPOS  784
#define NPOOL 1568
#define CELLS 196
#define TPB   448
#define WP    30
#define PIMG  900

__global__ __launch_bounds__(448) void deform_net_kernel(
    const float* __restrict__ x,       // (B,1,28,28)
    const float* __restrict__ w_off,   // (18,1,3,3)
    const float* __restrict__ b_off,   // (18,)
    const float* __restrict__ w_conv,  // (8,1,3,3)
    const float* __restrict__ w_fc,    // (10,1568)
    const float* __restrict__ b_fc,    // (10,)
    float* __restrict__ out,           // (B,10)
    int Btot)
{
    __shared__ float xs[2 * PIMG];     // two zero-padded 30x30 images
    __shared__ float wo_s[162];
    __shared__ float bo_s[18];
    __shared__ float wc_s[72];
    __shared__ float red[7][2][10];    // [wave][image-slot][channel]

    const int tid      = threadIdx.x;
    const int imgFirst = blockIdx.x * 2;

    if (tid < 162) wo_s[tid] = w_off[tid];
    if (tid < 18)  bo_s[tid] = b_off[tid];
    if (tid < 72)  wc_s[tid] = w_conv[tid];
    if (tid < 140) (&red[0][0][0])[tid] = 0.f;

    // Stage two zero-padded images into LDS.
    for (int i = tid; i < 2 * PIMG; i += TPB) {
        int s = i >= PIMG;             // image slot 0/1
        int v = i - s * PIMG;
        int r = v / WP, c = v - r * WP;
        int img = imgFirst + s;
        float val = 0.f;
        if (img < Btot && r >= 1 && r <= 28 && c >= 1 && c <= 28)
            val = x[(size_t)img * NPOS + (r - 1) * 28 + (c - 1)];
        xs[i] = val;
    }
    __syncthreads();

    const int slot = tid >= CELLS;     // which of the block's 2 images
    const int cim  = tid - slot * CELLS;   // cell within image (0..195)
    const float* __restrict__ xsl = xs + slot * PIMG;

    float fc[10];
    #pragma unroll
    for (int c = 0; c < 10; c++) fc[c] = 0.f;

    if (tid < 2 * CELLS && imgFirst + slot < Btot) {
        const int ph = cim / 14, pw = cim - (cim / 14) * 14;
        const int h0 = 2 * ph, w0 = 2 * pw;

        // 4x4 padded-image neighborhood covering all 4 positions' taps.
        float nb[16];
        #pragma unroll
        for (int i = 0; i < 4; i++)
            #pragma unroll
            for (int j = 0; j < 4; j++)
                nb[i * 4 + j] = xsl[(h0 + i) * WP + (w0 + j)];

        // ---- r10 champion body, FROZEN (k-outer, acc[4][8]) ----
        float acc[4][8];
        #pragma unroll
        for (int p = 0; p < 4; p++)
            #pragma unroll
            for (int o = 0; o < 8; o++) acc[p][o] = 0.f;

        #pragma unroll
        for (int k = 0; k < 9; k++) {          // deform tap
            const int kx = k / 3, ky = k % 3;
            #pragma unroll
            for (int p = 0; p < 4; p++) {      // position within pool cell
                const int dh = p >> 1, dw = p & 1;

                // offset channels k (x), k+9 (y): 3x3 conv at (h0+dh, w0+dw)
                float offx = bo_s[k], offy = bo_s[k + 9];
                #pragma unroll
                for (int t = 0; t < 9; t++) {
                    float nv = nb[(dh + t / 3) * 4 + (dw + t % 3)];
                    offx = fmaf(wo_s[k * 9 + t],       nv, offx);
                    offy = fmaf(wo_s[(k + 9) * 9 + t], nv, offy);
                }

                // sample coords in padded frame: p0=(h+1,w+1), pn=(kx-1,ky-1)
                float p_x = (float)(h0 + dh + kx) + offx;
                float p_y = (float)(w0 + dw + ky) + offy;

                float q0x = floorf(p_x), q0y = floorf(p_y);
                float qltx = __builtin_amdgcn_fmed3f(q0x,       0.f, 29.f);
                float qlty = __builtin_amdgcn_fmed3f(q0y,       0.f, 29.f);
                float qrbx = __builtin_amdgcn_fmed3f(q0x + 1.f, 0.f, 29.f);
                float qrby = __builtin_amdgcn_fmed3f(q0y + 1.f, 0.f, 29.f);
                float px   = __builtin_amdgcn_fmed3f(p_x,       0.f, 29.f);
                float py   = __builtin_amdgcn_fmed3f(p_y,       0.f, 29.f);

                float gltx = 1.f + (qltx - px);
                float glty = 1.f + (qlty - py);
                float grbx = 1.f - (qrbx - px);
                float grby = 1.f - (qrby - py);

                int ilx = (int)qltx, ily = (int)qlty;
                int irx = (int)qrbx, iry = (int)qrby;

                float xlt = xsl[ilx * WP + ily];
                float xrb = xsl[irx * WP + iry];
                float xlb = xsl[ilx * WP + iry];
                float xrt = xsl[irx * WP + ily];

                // factored bilinear combine (same clip semantics)
                float s = gltx * (glty * xlt + grby * xlb)
                        + grbx * (glty * xrt + grby * xrb);

                #pragma unroll
                for (int o = 0; o < 8; o++)
                    acc[p][o] = fmaf(wc_s[o * 9 + k], s, acc[p][o]);
            }
        }

        // relu + 2x2 maxpool in registers, then FC partials (o-outer).
        #pragma unroll
        for (int o = 0; o < 8; o++) {
            float m = fmaxf(fmaxf(acc[0][o], acc[1][o]),
                            fmaxf(acc[2][o], acc[3][o]));
            m = fmaxf(m, 0.f);
            const float* wrow = w_fc + o * CELLS + cim;  // flat idx o*196+cim
            #pragma unroll
            for (int c = 0; c < 10; c++)
                fc[c] = fmaf(m, wrow[c * NPOOL], fc[c]);
        }
        // ---- end frozen body ----
    }

    // Wave reduction. Only wave 3 (tids 192-255) straddles the image
    // boundary at 196; test is wave-uniform (scalar branch).
    const int wave = tid >> 6, lane = tid & 63;
    const int wc0  = wave << 6;
    const int sLo  = (wc0 >= CELLS);
    const int sHi  = (wc0 + 63 >= CELLS);

    if (sLo == sHi) {
        #pragma unroll
        for (int c = 0; c < 10; c++) {
            float a = fc[c];
            #pragma unroll
            for (int sh = 32; sh > 0; sh >>= 1)
                a += __shfl_down(a, sh, 64);
            if (lane == 0) red[wave][sLo][c] = a;
        }
    } else {
        const bool lo = (slot == 0);
        #pragma unroll
        for (int c = 0; c < 10; c++) {
            float a = lo ? fc[c] : 0.f;
            float b = lo ? 0.f : fc[c];
            #pragma unroll
            for (int sh = 32; sh > 0; sh >>= 1) {
                a += __shfl_down(a, sh, 64);
                b += __shfl_down(b, sh, 64);
            }
            if (lane == 0) {
                red[wave][0][c] = a;
                red[wave][1][c] = b;
            }
        }
    }
    __syncthreads();

    // Final: sum 7 waves per (slot, channel), add b_fc, direct store.
    if (tid < 20) {
        const int s = tid / 10, c = tid - (tid / 10) * 10;
        const int img = imgFirst + s;
        if (img < Btot) {
            float v = b_fc[c];
            #pragma unroll
            for (int w = 0; w < 7; w++) v += red[w][s][c];
            out[img * 10 + c] = v;
        }
    }
}

extern "C" void kernel_launch(void* const* d_in, const int* in_sizes, int n_in,
                              void* d_out, int out_size, void* d_ws, size_t ws_size,
                              hipStream_t stream) {
    const float* x      = (const float*)d_in[0];
    const float* w_off  = (const float*)d_in[1];
    const float* b_off  = (const float*)d_in[2];
    const float* w_conv = (const float*)d_in[3];
    const float* w_fc   = (const float*)d_in[4];
    const float* b_fc   = (const float*)d_in[5];
    float* out = (float*)d_out;

    const int B = in_sizes[0] / NPOS;
    const int nblk = (B + 1) / 2;      // 2048 for B=4096
    deform_net_kernel<<<nblk, TPB, 0, stream>>>(x, w_off, b_off, w_conv,
                                                w_fc, b_fc, out, B);
}